// Round 6
// baseline (302.774 us; speedup 1.0000x reference)
//
#include <hip/hip_runtime.h>
#include <hip/hip_bf16.h>
#include <stdint.h>
#include <math.h>

// Problem constants
#define BB 4
#define NN 2048
#define DD 1024
#define HH 16
#define HDD 64
#define SS 11

#define D4_0 0.4829629131445341f
#define D4_1 0.8365163037378079f
#define D4_2 0.2241438680420134f
#define D4_3 (-0.1294095225512604f)

typedef __bf16 bf16_t;
typedef __bf16 bf16x4_t __attribute__((ext_vector_type(4)));
typedef __bf16 bf16x8_t __attribute__((ext_vector_type(8)));
typedef float f32x4_t __attribute__((ext_vector_type(4)));

// ---------------- fused f32 -> bf16 conversion for all 4 tensors ----------------
__global__ __launch_bounds__(256) void cvt_all_k(const float* __restrict__ s0,
                                                 const float* __restrict__ s1,
                                                 const float* __restrict__ s2,
                                                 const float* __restrict__ s3,
                                                 bf16_t* __restrict__ d0,
                                                 bf16_t* __restrict__ d1,
                                                 bf16_t* __restrict__ d2,
                                                 bf16_t* __restrict__ d3) {
  const int n0 = 2097152, n1 = 786432, n2 = 262144, n3 = 262144;
  int i = blockIdx.x * 256 + threadIdx.x;
  const float* s;
  bf16_t* d;
  if (i < n0) { s = s0; d = d0; }
  else if (i < n0 + n1) { i -= n0; s = s1; d = d1; }
  else if (i < n0 + n1 + n2) { i -= n0 + n1; s = s2; d = d2; }
  else { i -= n0 + n1 + n2; if (i >= n3) return; s = s3; d = d3; }
  f32x4_t v = ((const f32x4_t*)s)[i];
  bf16x4_t o;
  o[0] = (bf16_t)v[0]; o[1] = (bf16_t)v[1]; o[2] = (bf16_t)v[2]; o[3] = (bf16_t)v[3];
  ((bf16x4_t*)d)[i] = o;
}

// ---------------- async global->LDS helper ----------------
__device__ __forceinline__ void gload16(const void* g, void* l) {
  __builtin_amdgcn_global_load_lds((__attribute__((address_space(1))) void*)(void*)g,
                                   (__attribute__((address_space(3))) void*)l,
                                   16, 0, 0);
}

// ================= 256x256 merged-window GEMM (R6), NT, K=1024 =================
// R5 post-mortem: reg-bank pipelining spilled (WRITE_SIZE +4MB) -> reverted.
// R2-R5: four schedule variants all ~92us / MfmaUtil 30%. Budget per phase
// (1725 cy): MFMA 160, LDS reads 430-580, VALU 350, stages 130 -> missing
// 500-700 cy = barrier+waitcnt framing, paid 16x per iter.
// R6: merge phase pairs. Window = one k-slice x both row-halves = 32 MFMA,
// 12 ds_read_b128 issued pre-barrier; lgkmcnt(0) after barrier (+rule-#18
// fence). 8 barriers/iter instead of 16, same read/MFMA totals, no reg banks.
// Stage plan: W1 stages O(2it+1) full -> buf1 (prev buf1 tile last read W4(it-1),
// all waves past that exit barrier); W2-exit vmcnt(0) drains O before W3 reads.
// W3 stages E2(2it+2) -> buf0 (buf0 last read W2); W4-exit vmcnt(0) drains E2.
__global__ __launch_bounds__(512, 2) void gemm256(const bf16_t* __restrict__ Aa,
                                                  const bf16_t* __restrict__ Bw,
                                                  const float* __restrict__ bias0,
                                                  const float* __restrict__ bias1,
                                                  bf16_t* __restrict__ out0,
                                                  bf16_t* __restrict__ out1) {
  __shared__ bf16_t sA[2][16384];  // [buf][256 rows x 64 k]
  __shared__ bf16_t sB[2][16384];

  const int tid = threadIdx.x;
  // XCD-bijective swizzle (512 blocks, 512%8==0)
  const int s = (blockIdx.x & 7) * 64 + (blockIdx.x >> 3);
  const int mtile = s >> 4;
  const int ntile = s & 15;
  const int row0 = mtile << 8;
  const int col0 = ntile << 8;

  const int w = tid >> 6, lane = tid & 63;
  const int wm = w >> 2, wn = w & 3;
  const int wmbase = wm << 7;
  const int wnbase = wn << 6;
  const int m16 = lane & 15, quad = lane >> 4;

  f32x4_t acc[8][4];
#pragma unroll
  for (int i = 0; i < 8; i++)
#pragma unroll
    for (int jq = 0; jq < 4; jq++) acc[i][jq] = (f32x4_t){0.f, 0.f, 0.f, 0.f};

  // stage one half-tile: tensor 0=A,1=B ; half 0/1 ; t = K-tile idx (2 loads/thread)
  auto stage_half = [&](int buf, int tensor, int half, int t) {
    if (t >= 16) return;  // block-uniform guard
    const bf16_t* gb = tensor ? Bw : Aa;
    const int gr0 = (tensor ? col0 : row0) + (half << 7);
    const int kb = t << 6;
    bf16_t* lbase = (tensor ? sB[buf] : sA[buf]) + (half << 13);
#pragma unroll
    for (int l = 0; l < 2; ++l) {
      int c = l * 512 + tid;
      int row = c >> 3, kc = c & 7;
      int swz = kc ^ (row & 7);  // pre-swizzled global source (T2)
      const bf16_t* g = gb + (size_t)(gr0 + row) * 1024 + kb + swz * 8;
      bf16_t* lp = lbase + ((l * 512 + (tid & 448)) << 3);
      gload16(g, lp);
    }
  };

  bf16x8_t af[8], bfr[4];
  auto rdA8 = [&](int buf, int ks) {
#pragma unroll
    for (int i = 0; i < 8; i++) {
      int ar = wmbase + (i << 4) + m16;
      int kc = (ks << 2) + quad;
      af[i] = *(const bf16x8_t*)&sA[buf][ar * 64 + ((kc ^ (ar & 7)) << 3)];
    }
  };
  auto rdB = [&](int buf, int ks) {
#pragma unroll
    for (int jq = 0; jq < 4; jq++) {
      int br = wnbase + (jq << 4) + m16;
      int kc = (ks << 2) + quad;
      bfr[jq] = *(const bf16x8_t*)&sB[buf][br * 64 + ((kc ^ (br & 7)) << 3)];
    }
  };
  auto domfma32 = [&]() {
#pragma unroll
    for (int i = 0; i < 8; i++)
#pragma unroll
      for (int jq = 0; jq < 4; jq++)
        acc[i][jq] =
            __builtin_amdgcn_mfma_f32_16x16x32_bf16(af[i], bfr[jq], acc[i][jq], 0, 0, 0);
  };

#define BAR() __builtin_amdgcn_s_barrier()
#define WAITL0() asm volatile("s_waitcnt lgkmcnt(0)" ::: "memory"); __builtin_amdgcn_sched_barrier(0)
#define PRIO1() __builtin_amdgcn_s_setprio(1)
#define PRIO0() __builtin_amdgcn_s_setprio(0)
#define WAITV0() asm volatile("s_waitcnt vmcnt(0)" ::: "memory")

  // Prologue: T0 full -> buf0; drain; barrier.
  stage_half(0, 0, 0, 0); stage_half(0, 0, 1, 0);
  stage_half(0, 1, 0, 0); stage_half(0, 1, 1, 0);
  WAITV0();
  BAR();

  for (int it = 0; it < 8; ++it) {
    const int O = 2 * it + 1, E2 = 2 * it + 2;
    // W1: reads buf0 ks0 ; stage O full -> buf1
    rdA8(0, 0); rdB(0, 0);
    stage_half(1, 0, 0, O); stage_half(1, 0, 1, O);
    stage_half(1, 1, 0, O); stage_half(1, 1, 1, O);
    BAR(); WAITL0(); PRIO1(); domfma32(); PRIO0(); BAR();
    // W2: reads buf0 ks1 ; exit drains O (before W3 reads buf1)
    rdA8(0, 1); rdB(0, 1);
    BAR(); WAITL0(); PRIO1(); domfma32(); PRIO0(); WAITV0(); BAR();
    // W3: reads buf1 ks0 ; stage E2 full -> buf0 (buf0 last read W2)
    rdA8(1, 0); rdB(1, 0);
    stage_half(0, 0, 0, E2); stage_half(0, 0, 1, E2);
    stage_half(0, 1, 0, E2); stage_half(0, 1, 1, E2);
    BAR(); WAITL0(); PRIO1(); domfma32(); PRIO0(); BAR();
    // W4: reads buf1 ks1 ; exit drains E2 (before next W1 reads buf0)
    rdA8(1, 1); rdB(1, 1);
    BAR(); WAITL0(); PRIO1(); domfma32(); PRIO0(); WAITV0(); BAR();
  }
#undef BAR
#undef WAITL0
#undef PRIO1
#undef PRIO0
#undef WAITV0

  // Epilogue: block-uniform qkv/gate split
  const bool is_gate = (col0 >= 3072);
#pragma unroll
  for (int i = 0; i < 8; i++) {
#pragma unroll
    for (int jq = 0; jq < 4; jq++) {
      const int grow0 = row0 + wmbase + (i << 4) + (quad << 2);
      const int gcol = col0 + wnbase + (jq << 4) + m16;
      const float bval = is_gate ? bias1[gcol - 3072] : bias0[gcol];
#pragma unroll
      for (int r = 0; r < 4; r++) {
        float val = acc[i][jq][r] + bval;
        if (is_gate)
          out1[(size_t)(grow0 + r) * 1024 + (gcol - 3072)] =
              (bf16_t)(1.f / (1.f + __expf(-val)));
        else
          out0[(size_t)(grow0 + r) * 3072 + gcol] = (bf16_t)val;
      }
    }
  }
}

// ---------------- NT bf16 GEMM (128^2, kept for GEMM-B) ----------------
template <int MODE>
__global__ __launch_bounds__(256) void gemm_nt(const bf16_t* __restrict__ A,
                                               const bf16_t* __restrict__ Bw,
                                               const float* __restrict__ bias0,
                                               const float* __restrict__ bias1,
                                               void* __restrict__ out0v,
                                               void* __restrict__ out1v,
                                               int M, int Nn, int K) {
  __shared__ bf16_t As[128 * 64];
  __shared__ bf16_t Bs[128 * 64];

  const int tid = threadIdx.x;
  const int ntiles = Nn >> 7;
  const int grp = ntiles << 3;
  const int g = blockIdx.x / grp;
  const int j = blockIdx.x % grp;
  const int mtile = (g << 3) | (j & 7);
  const int ntile = j >> 3;
  const int row0 = mtile << 7;
  const int col0 = ntile << 7;
  const int w = tid >> 6, lane = tid & 63;
  const int wm = w >> 1, wn = w & 1;
  const int m16 = lane & 15, quad = lane >> 4;

  f32x4_t acc[4][4];
#pragma unroll
  for (int i = 0; i < 4; i++)
#pragma unroll
    for (int jj = 0; jj < 4; jj++) acc[i][jj] = (f32x4_t){0.f, 0.f, 0.f, 0.f};

  for (int kb = 0; kb < K; kb += 64) {
    __syncthreads();
#pragma unroll
    for (int r = 0; r < 4; ++r) {
      int c = r * 256 + tid;
      int row = c >> 3, kc = c & 7;
      int swz = kc ^ (row & 7);
      const bf16_t* gpA = A + (size_t)(row0 + row) * K + kb + swz * 8;
      const bf16_t* gpB = Bw + (size_t)(col0 + row) * K + kb + swz * 8;
      bf16_t* lpA = As + (size_t)(r * 256 + (tid & 192)) * 8;
      bf16_t* lpB = Bs + (size_t)(r * 256 + (tid & 192)) * 8;
      gload16(gpA, lpA);
      gload16(gpB, lpB);
    }
    __syncthreads();

#pragma unroll
    for (int kk = 0; kk < 2; ++kk) {
      bf16x8_t af[4], bfr[4];
      const int kc = (kk << 2) + quad;
#pragma unroll
      for (int i = 0; i < 4; i++) {
        int arow = (wm << 6) + (i << 4) + m16;
        af[i] = *(const bf16x8_t*)(As + arow * 64 + ((kc ^ (arow & 7)) << 3));
        int brow = (wn << 6) + (i << 4) + m16;
        bfr[i] = *(const bf16x8_t*)(Bs + brow * 64 + ((kc ^ (brow & 7)) << 3));
      }
#pragma unroll
      for (int i = 0; i < 4; i++)
#pragma unroll
        for (int jj = 0; jj < 4; jj++)
          acc[i][jj] = __builtin_amdgcn_mfma_f32_16x16x32_bf16(af[i], bfr[jj], acc[i][jj], 0, 0, 0);
    }
  }

#pragma unroll
  for (int i = 0; i < 4; i++) {
#pragma unroll
    for (int jj = 0; jj < 4; jj++) {
      const int grow0 = row0 + (wm << 6) + (i << 4) + (quad << 2);
      const int gcol = col0 + (wn << 6) + (jj << 4) + m16;
      const float bval = (MODE == 0)
                             ? (gcol < 3072 ? bias0[gcol] : bias1[gcol - 3072])
                             : bias0[gcol];
#pragma unroll
      for (int r = 0; r < 4; r++) {
        float val = acc[i][jj][r] + bval;
        if (MODE == 0) {
          if (gcol < 3072)
            ((bf16_t*)out0v)[(size_t)(grow0 + r) * 3072 + gcol] = (bf16_t)val;
          else
            ((bf16_t*)out1v)[(size_t)(grow0 + r) * 1024 + (gcol - 3072)] =
                (bf16_t)(1.f / (1.f + __expf(-val)));
        } else {
          ((float*)out0v)[(size_t)(grow0 + r) * Nn + gcol] = val;
        }
      }
    }
  }
}

// ---------------- field + gains via MFMA: one wave per bn (16 heads) ----------------
__global__ __launch_bounds__(256) void field_gains_k(const bf16_t* __restrict__ qkvb,
                                                     const float* __restrict__ scale_gain,
                                                     const float* __restrict__ Wqs,
                                                     bf16_t* __restrict__ fieldb,
                                                     float* __restrict__ gains) {
  __shared__ float skmag[4 * 16];
  const int tid = threadIdx.x;
  const int w = tid >> 6, lane = tid & 63;
  const int bn = blockIdx.x * 4 + w;  // 0..8191
  const int b = bn >> 11, n_pos = bn & 2047;
  const int m16 = lane & 15, quad = lane >> 4;
  const bf16_t* qp = qkvb + (size_t)bn * 3072;

  bf16x8_t aq[2], ak[2], bw[2];
#pragma unroll
  for (int it = 0; it < 2; it++) {
    const int koff = it * 32 + quad * 8;
    aq[it] = *(const bf16x8_t*)(qp + m16 * 64 + koff);
    ak[it] = *(const bf16x8_t*)(qp + 1024 + m16 * 64 + koff);
    bf16x8_t bwv;
    if (m16 < SS) {
      const float* wp = Wqs + m16 * 64 + koff;
#pragma unroll
      for (int j = 0; j < 8; j++) bwv[j] = (bf16_t)wp[j];
    } else {
#pragma unroll
      for (int j = 0; j < 8; j++) bwv[j] = (bf16_t)0.f;
    }
    bw[it] = bwv;
  }

  f32x4_t acc_l = (f32x4_t){0.f, 0.f, 0.f, 0.f};
  f32x4_t acc_k = (f32x4_t){0.f, 0.f, 0.f, 0.f};
#pragma unroll
  for (int it = 0; it < 2; it++) {
    acc_l = __builtin_amdgcn_mfma_f32_16x16x32_bf16(aq[it], bw[it], acc_l, 0, 0, 0);
    acc_k = __builtin_amdgcn_mfma_f32_16x16x32_bf16(ak[it], ak[it], acc_k, 0, 0, 0);
  }

#pragma unroll
  for (int r = 0; r < 4; r++) {
    if (m16 == quad * 4 + r) skmag[w * 16 + m16] = sqrtf(fmaxf(acc_k[r], 0.f));
  }

#pragma unroll
  for (int r = 0; r < 4; r++) {
    const int m = quad * 4 + r;
    float lg = (m16 < SS) ? (acc_l[r] + scale_gain[m16 * 16 + m]) : -1e30f;
    float mx = lg;
#pragma unroll
    for (int sh = 1; sh < 16; sh <<= 1) mx = fmaxf(mx, __shfl_xor(mx, sh, 64));
    float e = (m16 < SS) ? __expf(lg - mx) : 0.f;
    float se = e;
#pragma unroll
    for (int sh = 1; sh < 16; sh <<= 1) se += __shfl_xor(se, sh, 64);
    if (m16 < SS)
      gains[((size_t)(b * 16 + m) * 2048 + n_pos) * SS + m16] = e / se;
  }

  __syncthreads();

#pragma unroll
  for (int h = 0; h < 16; h++) {
    const float km = skmag[w * 16 + h];
    const float v = (float)qp[2048 + h * 64 + lane];
    fieldb[((size_t)(b * 16 + h) * 2048 + n_pos) * 64 + lane] = (bf16_t)(v * km);
  }
}

// ======== fused multiscale conv + head coupling + gate (R6) ========
// Block = (b, 16-position n-tile); 16 waves, wave w = head w.
// Phase 1: conv (same math as old conv_k) -> LDS [16h][16n][64hd] bf16 (32KB).
// Phase 2: coupling softmax-mix across heads (softmax computed once/block) +
// sigmoid-gate multiply + gmat write. Eliminates facc (32MB HBM round trip)
// and the 8192-tiny-block couple_gate kernel.
__global__ __launch_bounds__(1024) void conv_couple_k(const bf16_t* __restrict__ field,
                                                      const float* __restrict__ gains,
                                                      const float* __restrict__ fcoup,
                                                      const bf16_t* __restrict__ gate,
                                                      bf16_t* __restrict__ gmat) {
  __shared__ bf16_t fld[16 * 16 * 64];  // [h][n_local][hd]
  __shared__ float scn[256];
  const int tid = threadIdx.x;
  const int blk = blockIdx.x;
  const int b = blk >> 7;           // 0..3
  const int nt = blk & 127;         // 0..127
  const int n0 = nt * 16;

  // coupling softmax rows (once per block)
  if (tid < 16) {
    float row[16];
    float mx = -1e30f;
#pragma unroll
    for (int j = 0; j < 16; j++) { row[j] = fcoup[tid * 16 + j]; mx = fmaxf(mx, row[j]); }
    float se = 0.f;
#pragma unroll
    for (int j = 0; j < 16; j++) { row[j] = __expf(row[j] - mx); se += row[j]; }
    float inv = 1.f / se;
#pragma unroll
    for (int j = 0; j < 16; j++) scn[tid * 16 + j] = row[j] * inv;
  }

  const int w = tid >> 6, lane = tid & 63;   // w = head
  const int nsub = lane >> 3, c = lane & 7;
  const bf16_t* frow = field + ((size_t)(b * 16 + w)) * 2048 * 64;

  // Phase 1: conv for this head, 16 n positions (2 passes of 8)
#pragma unroll
  for (int p = 0; p < 2; ++p) {
    const int nl = p * 8 + nsub;
    const int n = n0 + nl;
    float g[SS];
    const float* gp = gains + ((size_t)(b * 16 + w) * 2048 + n) * SS;
#pragma unroll
    for (int s = 0; s < SS; s++) g[s] = gp[s];

    float acc[8];
    {
      bf16x8_t f0 = *(const bf16x8_t*)(frow + (size_t)n * 64 + c * 8);
#pragma unroll
      for (int q = 0; q < 8; q++) acc[q] = D4_3 * (float)f0[q];  // offset 0: sum_s g_s = 1
    }
#pragma unroll
    for (int j = 0; j < 11; j++) {       // offsets 2^j
      float wgt = D4_2 * g[j];
      if (j >= 1) wgt += D4_1 * g[j - 1];
      int rr = n - (1 << j);
      float wv = rr >= 0 ? wgt : 0.f;
      rr = rr >= 0 ? rr : 0;
      bf16x8_t fv = *(const bf16x8_t*)(frow + (size_t)rr * 64 + c * 8);
#pragma unroll
      for (int q = 0; q < 8; q++) acc[q] += wv * (float)fv[q];
    }
#pragma unroll
    for (int j = 0; j < 10; j++) {       // offsets 3*2^j
      int rr = n - (3 << j);
      float wv = rr >= 0 ? (D4_0 * g[j]) : 0.f;
      rr = rr >= 0 ? rr : 0;
      bf16x8_t fv = *(const bf16x8_t*)(frow + (size_t)rr * 64 + c * 8);
#pragma unroll
      for (int q = 0; q < 8; q++) acc[q] += wv * (float)fv[q];
    }
    bf16x8_t o;
#pragma unroll
    for (int q = 0; q < 8; q++) o[q] = (bf16_t)acc[q];
    *(bf16x8_t*)&fld[w * 1024 + nl * 64 + c * 8] = o;
  }

  __syncthreads();

  // Phase 2: out head i=w at (n, hd-chunk c): sum_j scn[w][j]*fld[j][n][.] * gate
#pragma unroll
  for (int p = 0; p < 2; ++p) {
    const int nl = p * 8 + nsub;
    const int n = n0 + nl;
    float s8[8];
#pragma unroll
    for (int q = 0; q < 8; q++) s8[q] = 0.f;
#pragma unroll
    for (int j = 0; j < 16; j++) {
      const float cw = scn[w * 16 + j];
      bf16x8_t v = *(const bf16x8_t*)&fld[j * 1024 + nl * 64 + c * 8];
#pragma unroll
      for (int q = 0; q < 8; q++) s8[q] += cw * (float)v[q];
    }
    const size_t base = ((size_t)(b * 2048 + n)) * 1024 + w * 64 + c * 8;
    bf16x8_t gt = *(const bf16x8_t*)(gate + base);
    bf16x8_t o;
#pragma unroll
    for (int q = 0; q < 8; q++) o[q] = (bf16_t)(s8[q] * (float)gt[q]);
    *(bf16x8_t*)(gmat + base) = o;
  }
}

// ---------------- launch ----------------
extern "C" void kernel_launch(void* const* d_in, const int* in_sizes, int n_in,
                              void* d_out, int out_size, void* d_ws, size_t ws_size,
                              hipStream_t stream) {
  (void)in_sizes; (void)n_in; (void)out_size; (void)ws_size;
  const float* x = (const float*)d_in[0];
  const float* Wqkv = (const float*)d_in[1];
  const float* bqkv = (const float*)d_in[2];
  const float* Wo = (const float*)d_in[3];
  const float* bo = (const float*)d_in[4];
  const float* Wg = (const float*)d_in[5];
  const float* bg = (const float*)d_in[6];
  const float* scale_gain = (const float*)d_in[7];
  const float* Wqs = (const float*)d_in[8];
  const float* fcoup = (const float*)d_in[9];

  char* ws = (char*)d_ws;
  size_t off = 0;
  auto alloc = [&](size_t bytes) {
    void* p = ws + off;
    off += (bytes + 255) & ~(size_t)255;
    return p;
  };
  bf16_t* xb = (bf16_t*)alloc(8192ull * 1024 * 2);      // 16 MB
  bf16_t* Wab = (bf16_t*)alloc(4096ull * 1024 * 2);     // 8 MB (Wqkv rows then Wg rows)
  bf16_t* Wob = (bf16_t*)alloc(1024ull * 1024 * 2);     // 2 MB
  bf16_t* qkvb = (bf16_t*)alloc(8192ull * 3072 * 2);    // 48 MB
  bf16_t* gateb = (bf16_t*)alloc(8192ull * 1024 * 2);   // 16 MB
  bf16_t* fieldb = (bf16_t*)alloc(8388608ull * 2);      // 16 MB
  float* gains = (float*)alloc(8192ull * 16 * SS * 4);  // 5.8 MB
  bf16_t* gmat = (bf16_t*)alloc(8192ull * 1024 * 2);    // 16 MB

  // fused conversions (x, Wqkv, Wg, Wo)
  cvt_all_k<<<13316, 256, 0, stream>>>(x, Wqkv, Wg, Wo,
                                       xb, Wab, Wab + 3072ull * 1024, Wob);

  // GEMM-A: qkv + gate fused (M=8192, N=4096, K=1024), merged-window 256^2
  gemm256<<<512, 512, 0, stream>>>(xb, Wab, bqkv, bg, qkvb, gateb);

  // field + gains (MFMA-based, one wave per bn)
  field_gains_k<<<2048, 256, 0, stream>>>(qkvb, scale_gain, Wqs, fieldb, gains);

  // fused multiscale conv + coupling + gate
  conv_couple_k<<<512, 1024, 0, stream>>>(fieldb, gains, fcoup, gateb, gmat);

  // GEMM-B: output (M=8192, N=1024, K=1024), fp32 out
  gemm_nt<1><<<64 * 8, 256, 0, stream>>>(gmat, Wob, bo, nullptr, (void*)d_out, nullptr, 8192, 1024, 1024);
}

// Round 7
// 263.825 us; speedup vs baseline: 1.1476x; 1.1476x over previous
//
#include <hip/hip_runtime.h>
#include <hip/hip_bf16.h>
#include <stdint.h>
#include <math.h>

// Problem constants
#define BB 4
#define NN 2048
#define DD 1024
#define HH 16
#define HDD 64
#define SS 11

#define D4_0 0.4829629131445341f
#define D4_1 0.8365163037378079f
#define D4_2 0.2241438680420134f
#define D4_3 (-0.1294095225512604f)

typedef __bf16 bf16_t;
typedef __bf16 bf16x4_t __attribute__((ext_vector_type(4)));
typedef __bf16 bf16x8_t __attribute__((ext_vector_type(8)));
typedef float f32x4_t __attribute__((ext_vector_type(4)));

// ---------------- fused f32 -> bf16 conversion for all 4 tensors ----------------
__global__ __launch_bounds__(256) void cvt_all_k(const float* __restrict__ s0,
                                                 const float* __restrict__ s1,
                                                 const float* __restrict__ s2,
                                                 const float* __restrict__ s3,
                                                 bf16_t* __restrict__ d0,
                                                 bf16_t* __restrict__ d1,
                                                 bf16_t* __restrict__ d2,
                                                 bf16_t* __restrict__ d3) {
  const int n0 = 2097152, n1 = 786432, n2 = 262144, n3 = 262144;
  int i = blockIdx.x * 256 + threadIdx.x;
  const float* s;
  bf16_t* d;
  if (i < n0) { s = s0; d = d0; }
  else if (i < n0 + n1) { i -= n0; s = s1; d = d1; }
  else if (i < n0 + n1 + n2) { i -= n0 + n1; s = s2; d = d2; }
  else { i -= n0 + n1 + n2; if (i >= n3) return; s = s3; d = d3; }
  f32x4_t v = ((const f32x4_t*)s)[i];
  bf16x4_t o;
  o[0] = (bf16_t)v[0]; o[1] = (bf16_t)v[1]; o[2] = (bf16_t)v[2]; o[3] = (bf16_t)v[3];
  ((bf16x4_t*)d)[i] = o;
}

// ---------------- async global->LDS helper ----------------
__device__ __forceinline__ void gload16(const void* g, void* l) {
  __builtin_amdgcn_global_load_lds((__attribute__((address_space(1))) void*)(void*)g,
                                   (__attribute__((address_space(3))) void*)l,
                                   16, 0, 0);
}

// ================= 256x256 8-phase GEMM (R4 version — floor of record) =================
// R5/R6 post-mortem: unified VGPR/AGPR file. acc[8][4]=128 accum regs; at 2 waves/SIMD
// budget=256 -> 128 arch VGPRs left. R4 loop uses 112-116 (fits, 91.8us, 745 TF);
// R5 reg-banks (+64) and R6 af[8] (+24) both spilled (WRITE_SIZE +4MB/+24MB).
// Do NOT raise arch-VGPR in this kernel.
__global__ __launch_bounds__(512, 2) void gemm256(const bf16_t* __restrict__ Aa,
                                                  const bf16_t* __restrict__ Bw,
                                                  const float* __restrict__ bias0,
                                                  const float* __restrict__ bias1,
                                                  bf16_t* __restrict__ out0,
                                                  bf16_t* __restrict__ out1) {
  __shared__ bf16_t sA[2][16384];  // [buf][256 rows x 64 k]
  __shared__ bf16_t sB[2][16384];

  const int tid = threadIdx.x;
  // XCD-bijective swizzle (512 blocks, 512%8==0)
  const int s = (blockIdx.x & 7) * 64 + (blockIdx.x >> 3);
  const int mtile = s >> 4;
  const int ntile = s & 15;
  const int row0 = mtile << 8;
  const int col0 = ntile << 8;

  const int w = tid >> 6, lane = tid & 63;
  const int wm = w >> 2, wn = w & 3;
  const int wmbase = wm << 7;
  const int wnbase = wn << 6;
  const int m16 = lane & 15, quad = lane >> 4;

  f32x4_t acc[8][4];
#pragma unroll
  for (int i = 0; i < 8; i++)
#pragma unroll
    for (int jq = 0; jq < 4; jq++) acc[i][jq] = (f32x4_t){0.f, 0.f, 0.f, 0.f};

  // stage one half-tile: tensor 0=A,1=B ; half 0/1 ; t = K-tile idx (2 loads/thread)
  auto stage_half = [&](int buf, int tensor, int half, int t) {
    if (t >= 16) return;  // block-uniform guard
    const bf16_t* gb = tensor ? Bw : Aa;
    const int gr0 = (tensor ? col0 : row0) + (half << 7);
    const int kb = t << 6;
    bf16_t* lbase = (tensor ? sB[buf] : sA[buf]) + (half << 13);
#pragma unroll
    for (int l = 0; l < 2; ++l) {
      int c = l * 512 + tid;
      int row = c >> 3, kc = c & 7;
      int swz = kc ^ (row & 7);  // pre-swizzled global source (T2)
      const bf16_t* g = gb + (size_t)(gr0 + row) * 1024 + kb + swz * 8;
      bf16_t* lp = lbase + ((l * 512 + (tid & 448)) << 3);
      gload16(g, lp);
    }
  };

  bf16x8_t af[4], bfr[4];
  auto rdA = [&](int buf, int ih, int ks) {
#pragma unroll
    for (int i = 0; i < 4; i++) {
      int ar = wmbase + ((ih * 4 + i) << 4) + m16;
      int kc = (ks << 2) + quad;
      af[i] = *(const bf16x8_t*)&sA[buf][ar * 64 + ((kc ^ (ar & 7)) << 3)];
    }
  };
  auto rdB = [&](int buf, int ks) {
#pragma unroll
    for (int jq = 0; jq < 4; jq++) {
      int br = wnbase + (jq << 4) + m16;
      int kc = (ks << 2) + quad;
      bfr[jq] = *(const bf16x8_t*)&sB[buf][br * 64 + ((kc ^ (br & 7)) << 3)];
    }
  };
  auto domfma = [&](int ih) {
#pragma unroll
    for (int i = 0; i < 4; i++)
#pragma unroll
      for (int jq = 0; jq < 4; jq++)
        acc[ih * 4 + i][jq] =
            __builtin_amdgcn_mfma_f32_16x16x32_bf16(af[i], bfr[jq], acc[ih * 4 + i][jq], 0, 0, 0);
  };

// Minimal-fence phase framing (R4): barrier; lgkmcnt(0); rule-#18 fence; setprio(1);
// MFMA; setprio(0); [optional vmcnt]; barrier.
#define PH_ENTER()                                        \
  __builtin_amdgcn_s_barrier();                           \
  asm volatile("s_waitcnt lgkmcnt(0)" ::: "memory");      \
  __builtin_amdgcn_sched_barrier(0);                      \
  __builtin_amdgcn_s_setprio(1)
#define PH_EXIT()                                         \
  __builtin_amdgcn_s_setprio(0);                          \
  __builtin_amdgcn_s_barrier()
#define PH_EXIT_V4()                                      \
  __builtin_amdgcn_s_setprio(0);                          \
  asm volatile("s_waitcnt vmcnt(4)" ::: "memory");        \
  __builtin_amdgcn_s_barrier()
#define PH_EXIT_V0()                                      \
  __builtin_amdgcn_s_setprio(0);                          \
  asm volatile("s_waitcnt vmcnt(0)" ::: "memory");        \
  __builtin_amdgcn_s_barrier()

  // Prologue: T0 full (buf0) + T1.B (buf1 B both halves); vmcnt(4) leaves T1.B in flight.
  stage_half(0, 0, 0, 0); stage_half(0, 0, 1, 0);
  stage_half(0, 1, 0, 0); stage_half(0, 1, 1, 0);
  stage_half(1, 1, 0, 1); stage_half(1, 1, 1, 1);
  asm volatile("s_waitcnt vmcnt(4)" ::: "memory");
  __builtin_amdgcn_s_barrier();

  for (int it = 0; it < 8; ++it) {
    const int Tb = 2 * it + 1, T2 = 2 * it + 2, T3 = 2 * it + 3;
    // ph1: buf0 c1 ; stage Tb.A (buf1 A; freed prev ph8)
    rdA(0, 0, 0); rdB(0, 0);
    stage_half(1, 0, 0, Tb); stage_half(1, 0, 1, Tb);
    PH_ENTER(); domfma(0); PH_EXIT();
    // ph2: buf0 c2
    rdA(0, 1, 0);
    PH_ENTER(); domfma(1); PH_EXIT();
    // ph3: buf0 c3 (last read of buf0 B)
    rdA(0, 0, 1); rdB(0, 1);
    PH_ENTER(); domfma(0); PH_EXIT();
    // ph4: buf0 c4 (last read of buf0 A) ; stage T2.B (buf0 B) ; drain Tb, leave T2.B
    rdA(0, 1, 1);
    stage_half(0, 1, 0, T2); stage_half(0, 1, 1, T2);
    PH_ENTER(); domfma(1);
    if (T2 < 16) { PH_EXIT_V4(); } else { PH_EXIT_V0(); }
    // ph5: buf1 c1 ; stage T2.A (buf0 A)
    rdA(1, 0, 0); rdB(1, 0);
    stage_half(0, 0, 0, T2); stage_half(0, 0, 1, T2);
    PH_ENTER(); domfma(0); PH_EXIT();
    // ph6: buf1 c2
    rdA(1, 1, 0);
    PH_ENTER(); domfma(1); PH_EXIT();
    // ph7: buf1 c3 (last read of buf1 B)
    rdA(1, 0, 1); rdB(1, 1);
    PH_ENTER(); domfma(0); PH_EXIT();
    // ph8: buf1 c4 (last read of buf1 A) ; stage T3.B (buf1 B) ; drain T2, leave T3.B
    rdA(1, 1, 1);
    stage_half(1, 1, 0, T3); stage_half(1, 1, 1, T3);
    PH_ENTER(); domfma(1);
    if (T3 < 16) { PH_EXIT_V4(); } else { PH_EXIT_V0(); }
  }
#undef PH_ENTER
#undef PH_EXIT
#undef PH_EXIT_V4
#undef PH_EXIT_V0

  // Epilogue: block-uniform qkv/gate split
  const bool is_gate = (col0 >= 3072);
#pragma unroll
  for (int i = 0; i < 8; i++) {
#pragma unroll
    for (int jq = 0; jq < 4; jq++) {
      const int grow0 = row0 + wmbase + (i << 4) + (quad << 2);
      const int gcol = col0 + wnbase + (jq << 4) + m16;
      const float bval = is_gate ? bias1[gcol - 3072] : bias0[gcol];
#pragma unroll
      for (int r = 0; r < 4; r++) {
        float val = acc[i][jq][r] + bval;
        if (is_gate)
          out1[(size_t)(grow0 + r) * 1024 + (gcol - 3072)] =
              (bf16_t)(1.f / (1.f + __expf(-val)));
        else
          out0[(size_t)(grow0 + r) * 3072 + gcol] = (bf16_t)val;
      }
    }
  }
}

// ---------------- NT bf16 GEMM (128^2, kept for GEMM-B) ----------------
template <int MODE>
__global__ __launch_bounds__(256) void gemm_nt(const bf16_t* __restrict__ A,
                                               const bf16_t* __restrict__ Bw,
                                               const float* __restrict__ bias0,
                                               const float* __restrict__ bias1,
                                               void* __restrict__ out0v,
                                               void* __restrict__ out1v,
                                               int M, int Nn, int K) {
  __shared__ bf16_t As[128 * 64];
  __shared__ bf16_t Bs[128 * 64];

  const int tid = threadIdx.x;
  const int ntiles = Nn >> 7;
  const int grp = ntiles << 3;
  const int g = blockIdx.x / grp;
  const int j = blockIdx.x % grp;
  const int mtile = (g << 3) | (j & 7);
  const int ntile = j >> 3;
  const int row0 = mtile << 7;
  const int col0 = ntile << 7;
  const int w = tid >> 6, lane = tid & 63;
  const int wm = w >> 1, wn = w & 1;
  const int m16 = lane & 15, quad = lane >> 4;

  f32x4_t acc[4][4];
#pragma unroll
  for (int i = 0; i < 4; i++)
#pragma unroll
    for (int jj = 0; jj < 4; jj++) acc[i][jj] = (f32x4_t){0.f, 0.f, 0.f, 0.f};

  for (int kb = 0; kb < K; kb += 64) {
    __syncthreads();
#pragma unroll
    for (int r = 0; r < 4; ++r) {
      int c = r * 256 + tid;
      int row = c >> 3, kc = c & 7;
      int swz = kc ^ (row & 7);
      const bf16_t* gpA = A + (size_t)(row0 + row) * K + kb + swz * 8;
      const bf16_t* gpB = Bw + (size_t)(col0 + row) * K + kb + swz * 8;
      bf16_t* lpA = As + (size_t)(r * 256 + (tid & 192)) * 8;
      bf16_t* lpB = Bs + (size_t)(r * 256 + (tid & 192)) * 8;
      gload16(gpA, lpA);
      gload16(gpB, lpB);
    }
    __syncthreads();

#pragma unroll
    for (int kk = 0; kk < 2; ++kk) {
      bf16x8_t af[4], bfr[4];
      const int kc = (kk << 2) + quad;
#pragma unroll
      for (int i = 0; i < 4; i++) {
        int arow = (wm << 6) + (i << 4) + m16;
        af[i] = *(const bf16x8_t*)(As + arow * 64 + ((kc ^ (arow & 7)) << 3));
        int brow = (wn << 6) + (i << 4) + m16;
        bfr[i] = *(const bf16x8_t*)(Bs + brow * 64 + ((kc ^ (brow & 7)) << 3));
      }
#pragma unroll
      for (int i = 0; i < 4; i++)
#pragma unroll
        for (int jj = 0; jj < 4; jj++)
          acc[i][jj] = __builtin_amdgcn_mfma_f32_16x16x32_bf16(af[i], bfr[jj], acc[i][jj], 0, 0, 0);
    }
  }

#pragma unroll
  for (int i = 0; i < 4; i++) {
#pragma unroll
    for (int jj = 0; jj < 4; jj++) {
      const int grow0 = row0 + (wm << 6) + (i << 4) + (quad << 2);
      const int gcol = col0 + (wn << 6) + (jj << 4) + m16;
      const float bval = (MODE == 0)
                             ? (gcol < 3072 ? bias0[gcol] : bias1[gcol - 3072])
                             : bias0[gcol];
#pragma unroll
      for (int r = 0; r < 4; r++) {
        float val = acc[i][jj][r] + bval;
        if (MODE == 0) {
          if (gcol < 3072)
            ((bf16_t*)out0v)[(size_t)(grow0 + r) * 3072 + gcol] = (bf16_t)val;
          else
            ((bf16_t*)out1v)[(size_t)(grow0 + r) * 1024 + (gcol - 3072)] =
                (bf16_t)(1.f / (1.f + __expf(-val)));
        } else {
          ((float*)out0v)[(size_t)(grow0 + r) * Nn + gcol] = val;
        }
      }
    }
  }
}

// ---------------- field + gains via MFMA: one wave per bn (16 heads) ----------------
__global__ __launch_bounds__(256) void field_gains_k(const bf16_t* __restrict__ qkvb,
                                                     const float* __restrict__ scale_gain,
                                                     const float* __restrict__ Wqs,
                                                     bf16_t* __restrict__ fieldb,
                                                     float* __restrict__ gains) {
  __shared__ float skmag[4 * 16];
  const int tid = threadIdx.x;
  const int w = tid >> 6, lane = tid & 63;
  const int bn = blockIdx.x * 4 + w;  // 0..8191
  const int b = bn >> 11, n_pos = bn & 2047;
  const int m16 = lane & 15, quad = lane >> 4;
  const bf16_t* qp = qkvb + (size_t)bn * 3072;

  bf16x8_t aq[2], ak[2], bw[2];
#pragma unroll
  for (int it = 0; it < 2; it++) {
    const int koff = it * 32 + quad * 8;
    aq[it] = *(const bf16x8_t*)(qp + m16 * 64 + koff);
    ak[it] = *(const bf16x8_t*)(qp + 1024 + m16 * 64 + koff);
    bf16x8_t bwv;
    if (m16 < SS) {
      const float* wp = Wqs + m16 * 64 + koff;
#pragma unroll
      for (int j = 0; j < 8; j++) bwv[j] = (bf16_t)wp[j];
    } else {
#pragma unroll
      for (int j = 0; j < 8; j++) bwv[j] = (bf16_t)0.f;
    }
    bw[it] = bwv;
  }

  f32x4_t acc_l = (f32x4_t){0.f, 0.f, 0.f, 0.f};
  f32x4_t acc_k = (f32x4_t){0.f, 0.f, 0.f, 0.f};
#pragma unroll
  for (int it = 0; it < 2; it++) {
    acc_l = __builtin_amdgcn_mfma_f32_16x16x32_bf16(aq[it], bw[it], acc_l, 0, 0, 0);
    acc_k = __builtin_amdgcn_mfma_f32_16x16x32_bf16(ak[it], ak[it], acc_k, 0, 0, 0);
  }

#pragma unroll
  for (int r = 0; r < 4; r++) {
    if (m16 == quad * 4 + r) skmag[w * 16 + m16] = sqrtf(fmaxf(acc_k[r], 0.f));
  }

#pragma unroll
  for (int r = 0; r < 4; r++) {
    const int m = quad * 4 + r;
    float lg = (m16 < SS) ? (acc_l[r] + scale_gain[m16 * 16 + m]) : -1e30f;
    float mx = lg;
#pragma unroll
    for (int sh = 1; sh < 16; sh <<= 1) mx = fmaxf(mx, __shfl_xor(mx, sh, 64));
    float e = (m16 < SS) ? __expf(lg - mx) : 0.f;
    float se = e;
#pragma unroll
    for (int sh = 1; sh < 16; sh <<= 1) se += __shfl_xor(se, sh, 64);
    if (m16 < SS)
      gains[((size_t)(b * 16 + m) * 2048 + n_pos) * SS + m16] = e / se;
  }

  __syncthreads();

#pragma unroll
  for (int h = 0; h < 16; h++) {
    const float km = skmag[w * 16 + h];
    const float v = (float)qp[2048 + h * 64 + lane];
    fieldb[((size_t)(b * 16 + h) * 2048 + n_pos) * 64 + lane] = (bf16_t)(v * km);
  }
}

// ======== fused multiscale conv + head coupling + gate (kept from R6: ~15us win) ========
// Block = (b, 16-position n-tile); 16 waves, wave w = head w.
// Phase 1: conv -> LDS [16h][16n][64hd] bf16 (32KB). Phase 2: coupling softmax-mix
// (softmax once/block) + sigmoid-gate + gmat write. Eliminates facc round trip.
__global__ __launch_bounds__(1024) void conv_couple_k(const bf16_t* __restrict__ field,
                                                      const float* __restrict__ gains,
                                                      const float* __restrict__ fcoup,
                                                      const bf16_t* __restrict__ gate,
                                                      bf16_t* __restrict__ gmat) {
  __shared__ bf16_t fld[16 * 16 * 64];  // [h][n_local][hd]
  __shared__ float scn[256];
  const int tid = threadIdx.x;
  const int blk = blockIdx.x;
  const int b = blk >> 7;           // 0..3
  const int nt = blk & 127;         // 0..127
  const int n0 = nt * 16;

  // coupling softmax rows (once per block)
  if (tid < 16) {
    float row[16];
    float mx = -1e30f;
#pragma unroll
    for (int j = 0; j < 16; j++) { row[j] = fcoup[tid * 16 + j]; mx = fmaxf(mx, row[j]); }
    float se = 0.f;
#pragma unroll
    for (int j = 0; j < 16; j++) { row[j] = __expf(row[j] - mx); se += row[j]; }
    float inv = 1.f / se;
#pragma unroll
    for (int j = 0; j < 16; j++) scn[tid * 16 + j] = row[j] * inv;
  }

  const int w = tid >> 6, lane = tid & 63;   // w = head
  const int nsub = lane >> 3, c = lane & 7;
  const bf16_t* frow = field + ((size_t)(b * 16 + w)) * 2048 * 64;

  // Phase 1: conv for this head, 16 n positions (2 passes of 8)
#pragma unroll
  for (int p = 0; p < 2; ++p) {
    const int nl = p * 8 + nsub;
    const int n = n0 + nl;
    float g[SS];
    const float* gp = gains + ((size_t)(b * 16 + w) * 2048 + n) * SS;
#pragma unroll
    for (int s = 0; s < SS; s++) g[s] = gp[s];

    float acc[8];
    {
      bf16x8_t f0 = *(const bf16x8_t*)(frow + (size_t)n * 64 + c * 8);
#pragma unroll
      for (int q = 0; q < 8; q++) acc[q] = D4_3 * (float)f0[q];  // offset 0: sum_s g_s = 1
    }
#pragma unroll
    for (int j = 0; j < 11; j++) {       // offsets 2^j
      float wgt = D4_2 * g[j];
      if (j >= 1) wgt += D4_1 * g[j - 1];
      int rr = n - (1 << j);
      float wv = rr >= 0 ? wgt : 0.f;
      rr = rr >= 0 ? rr : 0;
      bf16x8_t fv = *(const bf16x8_t*)(frow + (size_t)rr * 64 + c * 8);
#pragma unroll
      for (int q = 0; q < 8; q++) acc[q] += wv * (float)fv[q];
    }
#pragma unroll
    for (int j = 0; j < 10; j++) {       // offsets 3*2^j
      int rr = n - (3 << j);
      float wv = rr >= 0 ? (D4_0 * g[j]) : 0.f;
      rr = rr >= 0 ? rr : 0;
      bf16x8_t fv = *(const bf16x8_t*)(frow + (size_t)rr * 64 + c * 8);
#pragma unroll
      for (int q = 0; q < 8; q++) acc[q] += wv * (float)fv[q];
    }
    bf16x8_t o;
#pragma unroll
    for (int q = 0; q < 8; q++) o[q] = (bf16_t)acc[q];
    *(bf16x8_t*)&fld[w * 1024 + nl * 64 + c * 8] = o;
  }

  __syncthreads();

  // Phase 2: out head i=w at (n, hd-chunk c): sum_j scn[w][j]*fld[j][n][.] * gate
#pragma unroll
  for (int p = 0; p < 2; ++p) {
    const int nl = p * 8 + nsub;
    const int n = n0 + nl;
    float s8[8];
#pragma unroll
    for (int q = 0; q < 8; q++) s8[q] = 0.f;
#pragma unroll
    for (int j = 0; j < 16; j++) {
      const float cw = scn[w * 16 + j];
      bf16x8_t v = *(const bf16x8_t*)&fld[j * 1024 + nl * 64 + c * 8];
#pragma unroll
      for (int q = 0; q < 8; q++) s8[q] += cw * (float)v[q];
    }
    const size_t base = ((size_t)(b * 2048 + n)) * 1024 + w * 64 + c * 8;
    bf16x8_t gt = *(const bf16x8_t*)(gate + base);
    bf16x8_t o;
#pragma unroll
    for (int q = 0; q < 8; q++) o[q] = (bf16_t)(s8[q] * (float)gt[q]);
    *(bf16x8_t*)(gmat + base) = o;
  }
}

// ---------------- launch ----------------
extern "C" void kernel_launch(void* const* d_in, const int* in_sizes, int n_in,
                              void* d_out, int out_size, void* d_ws, size_t ws_size,
                              hipStream_t stream) {
  (void)in_sizes; (void)n_in; (void)out_size; (void)ws_size;
  const float* x = (const float*)d_in[0];
  const float* Wqkv = (const float*)d_in[1];
  const float* bqkv = (const float*)d_in[2];
  const float* Wo = (const float*)d_in[3];
  const float* bo = (const float*)d_in[4];
  const float* Wg = (const float*)d_in[5];
  const float* bg = (const float*)d_in[6];
  const float* scale_gain = (const float*)d_in[7];
  const float* Wqs = (const float*)d_in[8];
  const float* fcoup = (const float*)d_in[9];

  char* ws = (char*)d_ws;
  size_t off = 0;
  auto alloc = [&](size_t bytes) {
    void* p = ws + off;
    off += (bytes + 255) & ~(size_t)255;
    return p;
  };
  bf16_t* xb = (bf16_t*)alloc(8192ull * 1024 * 2);      // 16 MB
  bf16_t* Wab = (bf16_t*)alloc(4096ull * 1024 * 2);     // 8 MB (Wqkv rows then Wg rows)
  bf16_t* Wob = (bf16_t*)alloc(1024ull * 1024 * 2);     // 2 MB
  bf16_t* qkvb = (bf16_t*)alloc(8192ull * 3072 * 2);    // 48 MB
  bf16_t* gateb = (bf16_t*)alloc(8192ull * 1024 * 2);   // 16 MB
  bf16_t* fieldb = (bf16_t*)alloc(8388608ull * 2);      // 16 MB
  float* gains = (float*)alloc(8192ull * 16 * SS * 4);  // 5.8 MB
  bf16_t* gmat = (bf16_t*)alloc(8192ull * 1024 * 2);    // 16 MB

  // fused conversions (x, Wqkv, Wg, Wo)
  cvt_all_k<<<13316, 256, 0, stream>>>(x, Wqkv, Wg, Wo,
                                       xb, Wab, Wab + 3072ull * 1024, Wob);

  // GEMM-A: qkv + gate fused (M=8192, N=4096, K=1024), 256^2 8-phase (R4)
  gemm256<<<512, 512, 0, stream>>>(xb, Wab, bqkv, bg, qkvb, gateb);

  // field + gains (MFMA-based, one wave per bn)
  field_gains_k<<<2048, 256, 0, stream>>>(qkvb, scale_gain, Wqs, fieldb, gains);

  // fused multiscale conv + coupling + gate
  conv_couple_k<<<512, 1024, 0, stream>>>(fieldb, gains, fcoup, gateb, gmat);

  // GEMM-B: output (M=8192, N=1024, K=1024), fp32 out
  gemm_nt<1><<<64 * 8, 256, 0, stream>>>(gmat, Wob, bo, nullptr, (void*)d_out, nullptr, 8192, 1024, 1024);
}